// Round 8
// baseline (385.238 us; speedup 1.0000x reference)
//
#include <hip/hip_runtime.h>
#include <hip/hip_bf16.h>
#include <stdint.h>

#define N_ENT 100000
#define EDIM 128
#define NHEAD 8
#define FDIM 512
#define NB 512
#define SEQ 12
#define CTXL 5
#define LN_EPS 1e-5f

typedef __attribute__((ext_vector_type(8))) short bf16x8;
typedef __attribute__((ext_vector_type(4))) float f32x4;
typedef __attribute__((ext_vector_type(16))) float f32x16;

__device__ __forceinline__ short f2bf(float f) {
  // compiler lowers __float2bfloat16 to v_cvt_pk_bf16_f32 pairs (RNE)
  __hip_bfloat16 h = __float2bfloat16(f);
  return (short)__bfloat16_as_ushort(h);
}

// ---------------- LN helper: wave w handles tokens w, w+4, w+8 -------------
__device__ __forceinline__ void ln_block(float (*src)[EDIM], float (*dst)[EDIM],
                                         const float* __restrict__ g,
                                         const float* __restrict__ be, int tid) {
  int wave = tid >> 6, lane = tid & 63;
  for (int t = wave; t < SEQ; t += 4) {
    float v0 = src[t][lane * 2], v1 = src[t][lane * 2 + 1];
    float sum = v0 + v1, sq = v0 * v0 + v1 * v1;
#pragma unroll
    for (int off = 32; off; off >>= 1) {
      sum += __shfl_xor(sum, off);
      sq += __shfl_xor(sq, off);
    }
    float mu = sum * (1.0f / 128.0f);
    float var = sq * (1.0f / 128.0f) - mu * mu;
    float rs = rsqrtf(var + LN_EPS);
    dst[t][lane * 2] = (v0 - mu) * rs * g[lane * 2] + be[lane * 2];
    dst[t][lane * 2 + 1] = (v1 - mu) * rs * g[lane * 2 + 1] + be[lane * 2 + 1];
  }
}

// ------- fused: gather -> 2 encoder layers -> prep (Abf + history) ---------
// One block per batch element. Encoder internals identical to the verified
// per-layer kernel; layers looped in-block (per-b independence). Epilogue
// writes A_bf16[512][256] row-major (registers consume it directly now) and
// the history output.
__global__ __launch_bounds__(256) void encoder_fused(
    const int* __restrict__ inp, const int* __restrict__ nextCheckin,
    const float* __restrict__ ctxSub, const float* __restrict__ ent,
    const float* __restrict__ ent_t, const float* __restrict__ rel,
    const float* __restrict__ rel_inv, const float* __restrict__ ctx,
    const float* __restrict__ Wqkv_, const float* __restrict__ bqkv_,
    const float* __restrict__ Wo_, const float* __restrict__ bo_,
    const float* __restrict__ W1_, const float* __restrict__ b1_,
    const float* __restrict__ W2_, const float* __restrict__ b2_,
    const float* __restrict__ g1_, const float* __restrict__ be1_,
    const float* __restrict__ g2_, const float* __restrict__ be2_,
    short* __restrict__ Abf, float* __restrict__ hist) {
  __shared__ float xs[SEQ][EDIM];        // 6 KB
  __shared__ float qkvs[SEQ][3 * EDIM];  // 18 KB
  __shared__ float atto[SEQ][EDIM];      // 6 KB
  __shared__ float h1s[SEQ][FDIM];       // 24 KB
  __shared__ float rbuf[SEQ][EDIM];      // 6 KB
  int b = blockIdx.x;
  int tid = threadIdx.x;

  // ---- gather (threads 0..127, e = tid; all t static) ----
  if (tid < EDIM) {
    int e = tid;
    int i0 = inp[0 * NB + b], i1 = inp[1 * NB + b], i2 = inp[2 * NB + b];
    xs[0][e] = ent[(size_t)i0 * EDIM + e];
    xs[1][e] = ent_t[(size_t)i0 * EDIM + e];
    xs[2][e] = rel[(size_t)i1 * EDIM + e];
    xs[3][e] = rel_inv[(size_t)i1 * EDIM + e];
    xs[4][e] = ent[(size_t)i2 * EDIM + e];
    xs[5][e] = ent_t[(size_t)i2 * EDIM + e];
#pragma unroll
    for (int j = 0; j < CTXL; ++j) {
      int c = inp[(3 + j) * NB + b];
      xs[6 + j][e] = ctx[(size_t)c * EDIM + e];
    }
    xs[11][e] = ctxSub[(size_t)b * EDIM + e];
  }
  __syncthreads();

  for (int l = 0; l < 2; ++l) {
    const float* Wqkv = Wqkv_ + l * 384 * 128;
    const float* bqkv = bqkv_ + l * 384;
    const float* Wo = Wo_ + l * 128 * 128;
    const float* bo = bo_ + l * 128;
    const float* W1 = W1_ + l * 512 * 128;
    const float* b1 = b1_ + l * 512;
    const float* W2 = W2_ + l * 128 * 512;
    const float* b2 = b2_ + l * 128;
    const float* g1 = g1_ + l * 128;
    const float* be1 = be1_ + l * 128;
    const float* g2 = g2_ + l * 128;
    const float* be2 = be2_ + l * 128;

    // qkv = x @ Wqkv.T + bqkv
    for (int o = tid; o < 3 * EDIM; o += 256) {
      const float* wr = Wqkv + o * EDIM;
      float bias = bqkv[o];
      float acc[SEQ];
#pragma unroll
      for (int t = 0; t < SEQ; ++t) acc[t] = bias;
      for (int e = 0; e < EDIM; e += 4) {
        float4 w = *(const float4*)(wr + e);
#pragma unroll
        for (int t = 0; t < SEQ; ++t)
          acc[t] += w.x * xs[t][e] + w.y * xs[t][e + 1] + w.z * xs[t][e + 2] +
                    w.w * xs[t][e + 3];
      }
#pragma unroll
      for (int t = 0; t < SEQ; ++t) qkvs[t][o] = acc[t];
    }
    __syncthreads();

    // attention: 96 threads, one (head, query-token) each; Dh=16, scale=0.25
    if (tid < NHEAD * SEQ) {
      int h = tid % NHEAD, tq = tid / NHEAD;
      const float scale = 0.25f;
      float s[SEQ];
      float mx = -1e30f;
#pragma unroll
      for (int tk = 0; tk < SEQ; ++tk) {
        float d = 0.f;
#pragma unroll
        for (int dd = 0; dd < 16; ++dd)
          d += qkvs[tq][h * 16 + dd] * qkvs[tk][EDIM + h * 16 + dd];
        s[tk] = d * scale;
        mx = fmaxf(mx, s[tk]);
      }
      float sum = 0.f;
#pragma unroll
      for (int tk = 0; tk < SEQ; ++tk) {
        s[tk] = __expf(s[tk] - mx);
        sum += s[tk];
      }
      float inv = 1.0f / sum;
#pragma unroll
      for (int dd = 0; dd < 16; ++dd) {
        float o = 0.f;
#pragma unroll
        for (int tk = 0; tk < SEQ; ++tk)
          o += s[tk] * qkvs[tk][2 * EDIM + h * 16 + dd];
        atto[tq][h * 16 + dd] = o * inv;
      }
    }
    __syncthreads();

    // out-proj + residual
    {
      int e = tid % EDIM, half = tid / EDIM;
      const float* wr = Wo + e * EDIM;
      float acc[6];
#pragma unroll
      for (int t = 0; t < 6; ++t) acc[t] = bo[e];
      for (int i = 0; i < EDIM; i += 4) {
        float4 w = *(const float4*)(wr + i);
#pragma unroll
        for (int t = 0; t < 6; ++t) {
          int tt = half * 6 + t;
          acc[t] += w.x * atto[tt][i] + w.y * atto[tt][i + 1] +
                    w.z * atto[tt][i + 2] + w.w * atto[tt][i + 3];
        }
      }
#pragma unroll
      for (int t = 0; t < 6; ++t) {
        int tt = half * 6 + t;
        rbuf[tt][e] = xs[tt][e] + acc[t];
      }
    }
    __syncthreads();
    ln_block(rbuf, xs, g1, be1, tid);
    __syncthreads();

    // FFN1 (relu)
    for (int f = tid; f < FDIM; f += 256) {
      const float* wr = W1 + f * EDIM;
      float bias = b1[f];
      float acc[SEQ];
#pragma unroll
      for (int t = 0; t < SEQ; ++t) acc[t] = bias;
      for (int e = 0; e < EDIM; e += 4) {
        float4 w = *(const float4*)(wr + e);
#pragma unroll
        for (int t = 0; t < SEQ; ++t)
          acc[t] += w.x * xs[t][e] + w.y * xs[t][e + 1] + w.z * xs[t][e + 2] +
                    w.w * xs[t][e + 3];
      }
#pragma unroll
      for (int t = 0; t < SEQ; ++t) h1s[t][f] = fmaxf(acc[t], 0.0f);
    }
    __syncthreads();

    // FFN2 + residual
    {
      int e = tid % EDIM, half = tid / EDIM;
      const float* wr = W2 + e * FDIM;
      float acc[6];
#pragma unroll
      for (int t = 0; t < 6; ++t) acc[t] = b2[e];
      for (int f = 0; f < FDIM; f += 4) {
        float4 w = *(const float4*)(wr + f);
#pragma unroll
        for (int t = 0; t < 6; ++t) {
          int tt = half * 6 + t;
          acc[t] += w.x * h1s[tt][f] + w.y * h1s[tt][f + 1] +
                    w.z * h1s[tt][f + 2] + w.w * h1s[tt][f + 3];
        }
      }
#pragma unroll
      for (int t = 0; t < 6; ++t) {
        int tt = half * 6 + t;
        rbuf[tt][e] = xs[tt][e] + acc[t];
      }
    }
    __syncthreads();
    ln_block(rbuf, xs, g2, be2, tid);
    __syncthreads();
  }

  // ---- prep epilogue: Abf rows (plain row-major) + history ----
  if (tid < EDIM) {
    int e = tid;
    int r = nextCheckin[1 * NB + b];
    float a0 = xs[0][e] * rel[(size_t)r * EDIM + e];
    float a1 = xs[1][e] * rel_inv[(size_t)r * EDIM + e];
    Abf[b * 256 + e] = f2bf(a0);
    Abf[b * 256 + 128 + e] = f2bf(a1);
    hist[(size_t)b * EDIM + e] = xs[11][e];
  }
}

// ---------------- scores: barrier-free A-in-register MFMA GEMM -------------
// M=512 N=100000 K=256. No LDS, no barriers. Each wave holds the A-fragments
// of one 32-row M-slice in 64 VGPRs (16x bf16x8, fully unrolled -> registers)
// and streams B (entity rows, fp32) global->reg->bf16->mfma_32x32x16 over 8
// col-groups of 32. Stores are full 128B lines (col = lane&31). Waves free-
// run; latency hidden by 12 waves/CU (launch_bounds 256,3) + load pipelining.
// Grid 1568 = 8*196: XCD-chunked swizzle gives each XCD 49 complete strips
// (all 4 M-tiles of a strip on one XCD -> B fetched from HBM once).
#define NSTRIP 392
__global__ __launch_bounds__(256, 3) void score_kernel(
    const short* __restrict__ Abf, const float* __restrict__ ent,
    const float* __restrict__ ent_t, float* __restrict__ out) {
  int tid = threadIdx.x, wave = tid >> 6, lane = tid & 63;
  int bid = blockIdx.x;
  int w = (bid & 7) * 196 + (bid >> 3);  // bijective: 1568 = 8*196
  int strip = w >> 2;                    // 0..391
  int mbase = (w & 3) * 128 + wave * 32; // this wave's 32 M-rows
  int l31 = lane & 31, half = lane >> 5;

  // A fragments: row = mbase + l31; frag f covers k = f*16 + half*8 .. +7
  const char* arow =
      (const char*)Abf + (size_t)(mbase + l31) * 512 + half * 16;
  bf16x8 af0  = *(const bf16x8*)(arow + 0 * 32);
  bf16x8 af1  = *(const bf16x8*)(arow + 1 * 32);
  bf16x8 af2  = *(const bf16x8*)(arow + 2 * 32);
  bf16x8 af3  = *(const bf16x8*)(arow + 3 * 32);
  bf16x8 af4  = *(const bf16x8*)(arow + 4 * 32);
  bf16x8 af5  = *(const bf16x8*)(arow + 5 * 32);
  bf16x8 af6  = *(const bf16x8*)(arow + 6 * 32);
  bf16x8 af7  = *(const bf16x8*)(arow + 7 * 32);
  bf16x8 af8  = *(const bf16x8*)(arow + 8 * 32);
  bf16x8 af9  = *(const bf16x8*)(arow + 9 * 32);
  bf16x8 af10 = *(const bf16x8*)(arow + 10 * 32);
  bf16x8 af11 = *(const bf16x8*)(arow + 11 * 32);
  bf16x8 af12 = *(const bf16x8*)(arow + 12 * 32);
  bf16x8 af13 = *(const bf16x8*)(arow + 13 * 32);
  bf16x8 af14 = *(const bf16x8*)(arow + 14 * 32);
  bf16x8 af15 = *(const bf16x8*)(arow + 15 * 32);

  for (int g = 0; g < 8; ++g) {
    int col = strip * 256 + g * 32 + l31;
    size_t nc = (col < N_ENT) ? (size_t)col : (size_t)(N_ENT - 1);
    const float* re = ent + nc * 128 + half * 8;   // k-halves per lane
    const float* rt = ent_t + nc * 128 + half * 8;

    f32x16 acc{};
#pragma unroll
    for (int f = 0; f < 16; ++f) {
      const float* s = (f < 8) ? (re + f * 16) : (rt + (f - 8) * 16);
      float4 u = *(const float4*)s;
      float4 v2 = *(const float4*)(s + 4);
      bf16x8 bf;
      bf[0] = f2bf(u.x);  bf[1] = f2bf(u.y);
      bf[2] = f2bf(u.z);  bf[3] = f2bf(u.w);
      bf[4] = f2bf(v2.x); bf[5] = f2bf(v2.y);
      bf[6] = f2bf(v2.z); bf[7] = f2bf(v2.w);
      bf16x8 a;
      switch (f) {
        case 0: a = af0; break;   case 1: a = af1; break;
        case 2: a = af2; break;   case 3: a = af3; break;
        case 4: a = af4; break;   case 5: a = af5; break;
        case 6: a = af6; break;   case 7: a = af7; break;
        case 8: a = af8; break;   case 9: a = af9; break;
        case 10: a = af10; break; case 11: a = af11; break;
        case 12: a = af12; break; case 13: a = af13; break;
        case 14: a = af14; break; default: a = af15; break;
      }
      acc = __builtin_amdgcn_mfma_f32_32x32x16_bf16(a, bf, acc, 0, 0, 0);
    }

    if (col < N_ENT) {
#pragma unroll
      for (int r = 0; r < 16; ++r) {
        int row = mbase + (r & 3) + 8 * (r >> 2) + 4 * half;
        float v = fminf(fmaxf(acc[r] * 0.5f, -20.0f), 20.0f);
        out[(size_t)row * N_ENT + col] = v;
      }
    }
  }
}

extern "C" void kernel_launch(void* const* d_in, const int* in_sizes, int n_in,
                              void* d_out, int out_size, void* d_ws,
                              size_t ws_size, hipStream_t stream) {
  const int* inp = (const int*)d_in[0];
  const int* nextCheckin = (const int*)d_in[1];
  const float* ctxSub = (const float*)d_in[2];
  const float* ent = (const float*)d_in[3];
  const float* ent_t = (const float*)d_in[4];
  const float* rel = (const float*)d_in[5];
  const float* rel_inv = (const float*)d_in[6];
  const float* ctx = (const float*)d_in[7];
  const float* Wqkv = (const float*)d_in[8];
  const float* bqkv = (const float*)d_in[9];
  const float* Wo = (const float*)d_in[10];
  const float* bo = (const float*)d_in[11];
  const float* W1 = (const float*)d_in[12];
  const float* b1 = (const float*)d_in[13];
  const float* W2 = (const float*)d_in[14];
  const float* b2 = (const float*)d_in[15];
  const float* g1 = (const float*)d_in[16];
  const float* be1 = (const float*)d_in[17];
  const float* g2 = (const float*)d_in[18];
  const float* be2 = (const float*)d_in[19];
  float* out = (float*)d_out;

  short* Abf = (short*)d_ws;                       // 256 KB
  float* hist = out + (size_t)NB * N_ENT;

  encoder_fused<<<NB, 256, 0, stream>>>(
      inp, nextCheckin, ctxSub, ent, ent_t, rel, rel_inv, ctx, Wqkv, bqkv, Wo,
      bo, W1, b1, W2, b2, g1, be1, g2, be2, Abf, hist);
  score_kernel<<<8 * 196, 256, 0, stream>>>(Abf, ent, ent_t, out);
}

// Round 9
// 381.944 us; speedup vs baseline: 1.0086x; 1.0086x over previous
//
#include <hip/hip_runtime.h>
#include <hip/hip_bf16.h>
#include <stdint.h>

#define N_ENT 100000
#define EDIM 128
#define NHEAD 8
#define FDIM 512
#define NB 512
#define SEQ 12
#define CTXL 5
#define LN_EPS 1e-5f

typedef __attribute__((ext_vector_type(8))) short bf16x8;
typedef __attribute__((ext_vector_type(4))) float f32x4;

__device__ __forceinline__ short f2bf(float f) {
  __hip_bfloat16 h = __float2bfloat16(f);
  return (short)__bfloat16_as_ushort(h);
}

// ---------------- LN helper: wave w handles tokens w, w+4, w+8 -------------
__device__ __forceinline__ void ln_block(float (*src)[EDIM], float (*dst)[EDIM],
                                         const float* __restrict__ g,
                                         const float* __restrict__ be, int tid) {
  int wave = tid >> 6, lane = tid & 63;
  for (int t = wave; t < SEQ; t += 4) {
    float v0 = src[t][lane * 2], v1 = src[t][lane * 2 + 1];
    float sum = v0 + v1, sq = v0 * v0 + v1 * v1;
#pragma unroll
    for (int off = 32; off; off >>= 1) {
      sum += __shfl_xor(sum, off);
      sq += __shfl_xor(sq, off);
    }
    float mu = sum * (1.0f / 128.0f);
    float var = sq * (1.0f / 128.0f) - mu * mu;
    float rs = rsqrtf(var + LN_EPS);
    dst[t][lane * 2] = (v0 - mu) * rs * g[lane * 2] + be[lane * 2];
    dst[t][lane * 2 + 1] = (v1 - mu) * rs * g[lane * 2 + 1] + be[lane * 2 + 1];
  }
}

// ------- fused: gather -> 2 encoder layers -> prep (swizzled Abf + hist) ---
__global__ __launch_bounds__(256) void encoder_fused(
    const int* __restrict__ inp, const int* __restrict__ nextCheckin,
    const float* __restrict__ ctxSub, const float* __restrict__ ent,
    const float* __restrict__ ent_t, const float* __restrict__ rel,
    const float* __restrict__ rel_inv, const float* __restrict__ ctx,
    const float* __restrict__ Wqkv_, const float* __restrict__ bqkv_,
    const float* __restrict__ Wo_, const float* __restrict__ bo_,
    const float* __restrict__ W1_, const float* __restrict__ b1_,
    const float* __restrict__ W2_, const float* __restrict__ b2_,
    const float* __restrict__ g1_, const float* __restrict__ be1_,
    const float* __restrict__ g2_, const float* __restrict__ be2_,
    short* __restrict__ Abfs, float* __restrict__ hist) {
  __shared__ float xs[SEQ][EDIM];
  __shared__ float qkvs[SEQ][3 * EDIM];
  __shared__ float atto[SEQ][EDIM];
  __shared__ float h1s[SEQ][FDIM];
  __shared__ float rbuf[SEQ][EDIM];
  int b = blockIdx.x;
  int tid = threadIdx.x;

  if (tid < EDIM) {
    int e = tid;
    int i0 = inp[0 * NB + b], i1 = inp[1 * NB + b], i2 = inp[2 * NB + b];
    xs[0][e] = ent[(size_t)i0 * EDIM + e];
    xs[1][e] = ent_t[(size_t)i0 * EDIM + e];
    xs[2][e] = rel[(size_t)i1 * EDIM + e];
    xs[3][e] = rel_inv[(size_t)i1 * EDIM + e];
    xs[4][e] = ent[(size_t)i2 * EDIM + e];
    xs[5][e] = ent_t[(size_t)i2 * EDIM + e];
#pragma unroll
    for (int j = 0; j < CTXL; ++j) {
      int c = inp[(3 + j) * NB + b];
      xs[6 + j][e] = ctx[(size_t)c * EDIM + e];
    }
    xs[11][e] = ctxSub[(size_t)b * EDIM + e];
  }
  __syncthreads();

  for (int l = 0; l < 2; ++l) {
    const float* Wqkv = Wqkv_ + l * 384 * 128;
    const float* bqkv = bqkv_ + l * 384;
    const float* Wo = Wo_ + l * 128 * 128;
    const float* bo = bo_ + l * 128;
    const float* W1 = W1_ + l * 512 * 128;
    const float* b1 = b1_ + l * 512;
    const float* W2 = W2_ + l * 128 * 512;
    const float* b2 = b2_ + l * 128;
    const float* g1 = g1_ + l * 128;
    const float* be1 = be1_ + l * 128;
    const float* g2 = g2_ + l * 128;
    const float* be2 = be2_ + l * 128;

    for (int o = tid; o < 3 * EDIM; o += 256) {
      const float* wr = Wqkv + o * EDIM;
      float bias = bqkv[o];
      float acc[SEQ];
#pragma unroll
      for (int t = 0; t < SEQ; ++t) acc[t] = bias;
      for (int e = 0; e < EDIM; e += 4) {
        float4 w = *(const float4*)(wr + e);
#pragma unroll
        for (int t = 0; t < SEQ; ++t)
          acc[t] += w.x * xs[t][e] + w.y * xs[t][e + 1] + w.z * xs[t][e + 2] +
                    w.w * xs[t][e + 3];
      }
#pragma unroll
      for (int t = 0; t < SEQ; ++t) qkvs[t][o] = acc[t];
    }
    __syncthreads();

    if (tid < NHEAD * SEQ) {
      int h = tid % NHEAD, tq = tid / NHEAD;
      const float scale = 0.25f;
      float s[SEQ];
      float mx = -1e30f;
#pragma unroll
      for (int tk = 0; tk < SEQ; ++tk) {
        float d = 0.f;
#pragma unroll
        for (int dd = 0; dd < 16; ++dd)
          d += qkvs[tq][h * 16 + dd] * qkvs[tk][EDIM + h * 16 + dd];
        s[tk] = d * scale;
        mx = fmaxf(mx, s[tk]);
      }
      float sum = 0.f;
#pragma unroll
      for (int tk = 0; tk < SEQ; ++tk) {
        s[tk] = __expf(s[tk] - mx);
        sum += s[tk];
      }
      float inv = 1.0f / sum;
#pragma unroll
      for (int dd = 0; dd < 16; ++dd) {
        float o = 0.f;
#pragma unroll
        for (int tk = 0; tk < SEQ; ++tk)
          o += s[tk] * qkvs[tk][2 * EDIM + h * 16 + dd];
        atto[tq][h * 16 + dd] = o * inv;
      }
    }
    __syncthreads();

    {
      int e = tid % EDIM, half = tid / EDIM;
      const float* wr = Wo + e * EDIM;
      float acc[6];
#pragma unroll
      for (int t = 0; t < 6; ++t) acc[t] = bo[e];
      for (int i = 0; i < EDIM; i += 4) {
        float4 w = *(const float4*)(wr + i);
#pragma unroll
        for (int t = 0; t < 6; ++t) {
          int tt = half * 6 + t;
          acc[t] += w.x * atto[tt][i] + w.y * atto[tt][i + 1] +
                    w.z * atto[tt][i + 2] + w.w * atto[tt][i + 3];
        }
      }
#pragma unroll
      for (int t = 0; t < 6; ++t) {
        int tt = half * 6 + t;
        rbuf[tt][e] = xs[tt][e] + acc[t];
      }
    }
    __syncthreads();
    ln_block(rbuf, xs, g1, be1, tid);
    __syncthreads();

    for (int f = tid; f < FDIM; f += 256) {
      const float* wr = W1 + f * EDIM;
      float bias = b1[f];
      float acc[SEQ];
#pragma unroll
      for (int t = 0; t < SEQ; ++t) acc[t] = bias;
      for (int e = 0; e < EDIM; e += 4) {
        float4 w = *(const float4*)(wr + e);
#pragma unroll
        for (int t = 0; t < SEQ; ++t)
          acc[t] += w.x * xs[t][e] + w.y * xs[t][e + 1] + w.z * xs[t][e + 2] +
                    w.w * xs[t][e + 3];
      }
#pragma unroll
      for (int t = 0; t < SEQ; ++t) h1s[t][f] = fmaxf(acc[t], 0.0f);
    }
    __syncthreads();

    {
      int e = tid % EDIM, half = tid / EDIM;
      const float* wr = W2 + e * FDIM;
      float acc[6];
#pragma unroll
      for (int t = 0; t < 6; ++t) acc[t] = b2[e];
      for (int f = 0; f < FDIM; f += 4) {
        float4 w = *(const float4*)(wr + f);
#pragma unroll
        for (int t = 0; t < 6; ++t) {
          int tt = half * 6 + t;
          acc[t] += w.x * h1s[tt][f] + w.y * h1s[tt][f + 1] +
                    w.z * h1s[tt][f + 2] + w.w * h1s[tt][f + 3];
        }
      }
#pragma unroll
      for (int t = 0; t < 6; ++t) {
        int tt = half * 6 + t;
        rbuf[tt][e] = xs[tt][e] + acc[t];
      }
    }
    __syncthreads();
    ln_block(rbuf, xs, g2, be2, tid);
    __syncthreads();
  }

  // ---- prep epilogue: swizzled Abfs (16B granule cg stored at cg^(b&31)) --
  if (tid < EDIM) {
    int e = tid;
    int r = nextCheckin[1 * NB + b];
    float a0 = xs[0][e] * rel[(size_t)r * EDIM + e];
    float a1 = xs[1][e] * rel_inv[(size_t)r * EDIM + e];
    int j = e & 7, s = b & 31;
    int cg0 = e >> 3;
    int cg1 = 16 + (e >> 3);
    Abfs[b * 256 + ((cg0 ^ s) << 3) + j] = f2bf(a0);
    Abfs[b * 256 + ((cg1 ^ s) << 3) + j] = f2bf(a1);
    hist[(size_t)b * EDIM + e] = xs[11][e];
  }
}

// ---------------- scores: counted-vmcnt pipelined MFMA GEMM ----------------
// M=512 N=100000 K=256. One block per 64-col N-strip (1563 blocks). B strip
// staged once (fp32->bf16, swizzled LDS); B-fragments hoisted to 32 VGPRs.
// A streamed as 16 chunks x 32 rows through a 3-buffer LDS rotation staged
// TWO chunks ahead via global_load_lds. Barriers are raw s_barrier with
// COUNTED vmcnt (steady vmcnt(20)) so the loop never drains fresh stage
// loads or the store queue (T3/T4). Store count kept wave-uniform (vmcnt
// arithmetic) by routing out-of-range waves' stores to a dump region.
__global__ __launch_bounds__(256, 2) void score_kernel(
    const short* __restrict__ Abfs, const float* __restrict__ ent,
    const float* __restrict__ ent_t, float* __restrict__ out,
    float* __restrict__ dump) {
  __shared__ char Bsb[32768];     // B strip [64][256] bf16, swizzled
  __shared__ char Asb[3][16384];  // A chunk rotation: 32 rows x 512B each

  int tid = threadIdx.x, wave = tid >> 6, lane = tid & 63;
  int nbase = blockIdx.x * 64;

  // ---- stage B strip: 64 rows x 256 k fp32 -> bf16, swizzled ds_write ----
#pragma unroll
  for (int i = 0; i < 16; ++i) {
    int flat = i * 256 + tid;
    int row = flat >> 6;
    int c4 = flat & 63;
    int n = nbase + row;
    float4 v = make_float4(0.f, 0.f, 0.f, 0.f);
    if (n < N_ENT) {
      const float* src = (c4 < 32) ? ent + (size_t)n * 128 + c4 * 4
                                   : ent_t + (size_t)n * 128 + (c4 - 32) * 4;
      v = *(const float4*)src;
    }
    short4 bb;
    bb.x = f2bf(v.x); bb.y = f2bf(v.y); bb.z = f2bf(v.z); bb.w = f2bf(v.w);
    int chunk = c4 >> 1, half = c4 & 1;
    *(short4*)(Bsb + row * 512 + ((chunk ^ (row & 7)) << 4) + half * 8) = bb;
  }
  asm volatile("" ::: "memory");  // pin: all B ops before A stage issues

  // ---- stage A chunks 0 and 1 ----
  const char* gA = (const char*)Abfs;
#pragma unroll
  for (int p = 0; p < 2; ++p) {
#pragma unroll
    for (int it = 0; it < 4; ++it) {
      int off = wave * 4096 + it * 1024;
      __builtin_amdgcn_global_load_lds(
          (const __attribute__((address_space(1))) uint32_t*)(
              gA + (size_t)p * 16384 + off + lane * 16),
          (__attribute__((address_space(3))) uint32_t*)(&Asb[p][0] + off), 16,
          0, 0);
    }
  }
  // A0 landed (4 newest = A1 may fly); B ds_writes visible
  asm volatile("s_waitcnt vmcnt(4) lgkmcnt(0)\n\ts_barrier" ::: "memory");

  int q = lane >> 4;   // 0..3 (k-quarter)
  int lr = lane & 15;
  int rb = wave * 16 + lr;
  int col = nbase + rb;
  bool cvalid = (col < N_ENT);  // wave-uniform (100000 % 16 == 0)
  float* dmp = dump + tid * 8;

  // hoist B fragments for all 8 k-steps (reused across 16 chunks)
  bf16x8 bfr[8];
#pragma unroll
  for (int ks = 0; ks < 8; ++ks) {
    int cg = ks * 4 + q;
    bfr[ks] = *(const bf16x8*)(Bsb + rb * 512 + ((cg ^ (rb & 7)) << 4));
  }

  float svA[8] = {0, 0, 0, 0, 0, 0, 0, 0};
  float svB[8] = {0, 0, 0, 0, 0, 0, 0, 0};

#pragma unroll
  for (int c = 0; c < 16; ++c) {
    // 1) stage chunk c+2 into buffer (c+2)%3 (distinct from c, c+1 parities)
    if (c + 2 < 16) {
      const char* src = gA + (size_t)(c + 2) * 16384;
      char* dst = &Asb[(c + 2) % 3][0];
#pragma unroll
      for (int it = 0; it < 4; ++it) {
        int off = wave * 4096 + it * 1024;
        __builtin_amdgcn_global_load_lds(
            (const __attribute__((address_space(1))) uint32_t*)(src + off +
                                                                lane * 16),
            (__attribute__((address_space(3))) uint32_t*)(dst + off), 16, 0, 0);
      }
    }
    asm volatile("" ::: "memory");

    // 2) stores of chunk c-1 (8 per wave, count-uniform via dump routing)
    if (c > 0) {
      const float* s = (c & 1) ? svA : svB;
      int rbase = (c - 1) * 32 + q * 4;
#pragma unroll
      for (int r = 0; r < 4; ++r) {
        volatile float* p0 =
            cvalid ? (volatile float*)(out + (size_t)(rbase + r) * N_ENT + col)
                   : (volatile float*)(dmp + r);
        *p0 = s[r];
        volatile float* p1 =
            cvalid
                ? (volatile float*)(out + (size_t)(rbase + 16 + r) * N_ENT + col)
                : (volatile float*)(dmp + 4 + r);
        *p1 = s[4 + r];
      }
    }
    asm volatile("" ::: "memory");

    // 3) compute chunk c from buffer c%3
    const char* base = &Asb[c % 3][0];
    f32x4 a0{}, a1{};
#pragma unroll
    for (int ks = 0; ks < 8; ++ks) {
      int cg = ks * 4 + q;
      int r0 = lr, r1 = 16 + lr;
      bf16x8 af0 = *(const bf16x8*)(base + r0 * 512 + ((cg ^ r0) << 4));
      bf16x8 af1 = *(const bf16x8*)(base + r1 * 512 + ((cg ^ r1) << 4));
      a0 = __builtin_amdgcn_mfma_f32_16x16x32_bf16(af0, bfr[ks], a0, 0, 0, 0);
      a1 = __builtin_amdgcn_mfma_f32_16x16x32_bf16(af1, bfr[ks], a1, 0, 0, 0);
    }
    float* d = (c & 1) ? svB : svA;
#pragma unroll
    for (int r = 0; r < 4; ++r) {
      d[r] = fminf(fmaxf(a0[r] * 0.5f, -20.0f), 20.0f);
      d[4 + r] = fminf(fmaxf(a1[r] * 0.5f, -20.0f), 20.0f);
    }

    // 4) counted wait (ensures stage(c+1) landed; never drains fresh ops)
    //    N = ops issued after stage(c+1): stores + stage(c+2) + stores
    if (c == 0)
      asm volatile("s_waitcnt vmcnt(4) lgkmcnt(0)\n\ts_barrier" ::: "memory");
    else if (c == 1)
      asm volatile("s_waitcnt vmcnt(12) lgkmcnt(0)\n\ts_barrier" ::: "memory");
    else if (c <= 13)
      asm volatile("s_waitcnt vmcnt(20) lgkmcnt(0)\n\ts_barrier" ::: "memory");
    else if (c == 14)
      asm volatile("s_waitcnt vmcnt(16) lgkmcnt(0)\n\ts_barrier" ::: "memory");
    // c == 15: last compute, no barrier needed
  }

  // epilogue: store chunk 15 (parity: odd -> svB)
  if (cvalid) {
    int rbase = 15 * 32 + q * 4;
#pragma unroll
    for (int r = 0; r < 4; ++r) {
      out[(size_t)(rbase + r) * N_ENT + col] = svB[r];
      out[(size_t)(rbase + 16 + r) * N_ENT + col] = svB[4 + r];
    }
  }
}

extern "C" void kernel_launch(void* const* d_in, const int* in_sizes, int n_in,
                              void* d_out, int out_size, void* d_ws,
                              size_t ws_size, hipStream_t stream) {
  const int* inp = (const int*)d_in[0];
  const int* nextCheckin = (const int*)d_in[1];
  const float* ctxSub = (const float*)d_in[2];
  const float* ent = (const float*)d_in[3];
  const float* ent_t = (const float*)d_in[4];
  const float* rel = (const float*)d_in[5];
  const float* rel_inv = (const float*)d_in[6];
  const float* ctx = (const float*)d_in[7];
  const float* Wqkv = (const float*)d_in[8];
  const float* bqkv = (const float*)d_in[9];
  const float* Wo = (const float*)d_in[10];
  const float* bo = (const float*)d_in[11];
  const float* W1 = (const float*)d_in[12];
  const float* b1 = (const float*)d_in[13];
  const float* W2 = (const float*)d_in[14];
  const float* b2 = (const float*)d_in[15];
  const float* g1 = (const float*)d_in[16];
  const float* be1 = (const float*)d_in[17];
  const float* g2 = (const float*)d_in[18];
  const float* be2 = (const float*)d_in[19];
  float* out = (float*)d_out;

  short* Abfs = (short*)d_ws;                            // 256 KB
  float* dump = (float*)((char*)d_ws + 262144);          // 8 KB dump area
  float* hist = out + (size_t)NB * N_ENT;

  encoder_fused<<<NB, 256, 0, stream>>>(
      inp, nextCheckin, ctxSub, ent, ent_t, rel, rel_inv, ctx, Wqkv, bqkv, Wo,
      bo, W1, b1, W2, b2, g1, be1, g2, be2, Abfs, hist);
  score_kernel<<<1563, 256, 0, stream>>>(Abfs, ent, ent_t, out, dump);
}

// Round 10
// 280.017 us; speedup vs baseline: 1.3758x; 1.3640x over previous
//
#include <hip/hip_runtime.h>
#include <hip/hip_bf16.h>
#include <stdint.h>

#define N_ENT 100000
#define EDIM 128
#define NHEAD 8
#define FDIM 512
#define NB 512
#define SEQ 12
#define CTXL 5
#define LN_EPS 1e-5f

typedef __attribute__((ext_vector_type(8))) short bf16x8;
typedef __attribute__((ext_vector_type(4))) float f32x4;

__device__ __forceinline__ short f2bf(float f) {
  __hip_bfloat16 h = __float2bfloat16(f);
  return (short)__bfloat16_as_ushort(h);
}

// ---- weight transpose: WT per layer = [WqkvT 128x384 | WoT 128x128 |
//      W1T 128x512 | W2T 512x128], coalesced-on-o layouts ----
#define LSTRIDE 196608
__global__ void wt_kernel(const float* __restrict__ Wqkv,
                          const float* __restrict__ Wo,
                          const float* __restrict__ W1,
                          const float* __restrict__ W2,
                          float* __restrict__ WT) {
  int idx = blockIdx.x * 256 + threadIdx.x;  // 0..393215
  int layer = idx / LSTRIDE;
  int r = idx % LSTRIDE;
  float* dst = WT + (size_t)layer * LSTRIDE;
  if (r < 49152) {           // WqkvT[e*384+o] = Wqkv[o*128+e]
    int e = r / 384, o = r % 384;
    dst[r] = Wqkv[layer * 49152 + o * 128 + e];
  } else if (r < 65536) {    // WoT[i*128+e] = Wo[e*128+i]
    int rr = r - 49152, i = rr / 128, e = rr % 128;
    dst[r] = Wo[layer * 16384 + e * 128 + i];
  } else if (r < 131072) {   // W1T[e*512+f] = W1[f*128+e]
    int rr = r - 65536, e = rr / 512, f = rr % 512;
    dst[r] = W1[layer * 65536 + f * 128 + e];
  } else {                   // W2T[f*128+e] = W2[e*512+f]
    int rr = r - 131072, f = rr / 128, e = rr % 128;
    dst[r] = W2[layer * 65536 + e * 512 + f];
  }
}

// ---------------- LN helper: wave w handles tokens w, w+4, w+8 -------------
__device__ __forceinline__ void ln_block(float (*src)[EDIM], float (*dst)[EDIM],
                                         const float* __restrict__ g,
                                         const float* __restrict__ be, int tid) {
  int wave = tid >> 6, lane = tid & 63;
  for (int t = wave; t < SEQ; t += 4) {
    float v0 = src[t][lane * 2], v1 = src[t][lane * 2 + 1];
    float sum = v0 + v1, sq = v0 * v0 + v1 * v1;
#pragma unroll
    for (int off = 32; off; off >>= 1) {
      sum += __shfl_xor(sum, off);
      sq += __shfl_xor(sq, off);
    }
    float mu = sum * (1.0f / 128.0f);
    float var = sq * (1.0f / 128.0f) - mu * mu;
    float rs = rsqrtf(var + LN_EPS);
    dst[t][lane * 2] = (v0 - mu) * rs * g[lane * 2] + be[lane * 2];
    dst[t][lane * 2 + 1] = (v1 - mu) * rs * g[lane * 2 + 1] + be[lane * 2 + 1];
  }
}

// ------- fused: gather -> 2 encoder layers -> prep (swizzled Abf + hist) ---
// All W reads go through the transposed copies: lane o reads WT[..*No + o]
// -> fully coalesced (the original per-thread-row reads were 64-way scatter).
__global__ __launch_bounds__(256) void encoder_fused(
    const int* __restrict__ inp, const int* __restrict__ nextCheckin,
    const float* __restrict__ ctxSub, const float* __restrict__ ent,
    const float* __restrict__ ent_t, const float* __restrict__ rel,
    const float* __restrict__ rel_inv, const float* __restrict__ ctx,
    const float* __restrict__ WT_, const float* __restrict__ bqkv_,
    const float* __restrict__ bo_, const float* __restrict__ b1_,
    const float* __restrict__ b2_, const float* __restrict__ g1_,
    const float* __restrict__ be1_, const float* __restrict__ g2_,
    const float* __restrict__ be2_, short* __restrict__ Abfs,
    float* __restrict__ hist) {
  __shared__ float xs[SEQ][EDIM];
  __shared__ float qkvs[SEQ][3 * EDIM];
  __shared__ float atto[SEQ][EDIM];
  __shared__ float h1s[SEQ][FDIM];
  __shared__ float rbuf[SEQ][EDIM];
  int b = blockIdx.x;
  int tid = threadIdx.x;

  if (tid < EDIM) {
    int e = tid;
    int i0 = inp[0 * NB + b], i1 = inp[1 * NB + b], i2 = inp[2 * NB + b];
    xs[0][e] = ent[(size_t)i0 * EDIM + e];
    xs[1][e] = ent_t[(size_t)i0 * EDIM + e];
    xs[2][e] = rel[(size_t)i1 * EDIM + e];
    xs[3][e] = rel_inv[(size_t)i1 * EDIM + e];
    xs[4][e] = ent[(size_t)i2 * EDIM + e];
    xs[5][e] = ent_t[(size_t)i2 * EDIM + e];
#pragma unroll
    for (int j = 0; j < CTXL; ++j) {
      int c = inp[(3 + j) * NB + b];
      xs[6 + j][e] = ctx[(size_t)c * EDIM + e];
    }
    xs[11][e] = ctxSub[(size_t)b * EDIM + e];
  }
  __syncthreads();

  for (int l = 0; l < 2; ++l) {
    const float* WqkvT = WT_ + (size_t)l * LSTRIDE;
    const float* WoT = WqkvT + 49152;
    const float* W1T = WqkvT + 65536;
    const float* W2T = WqkvT + 131072;
    const float* bqkv = bqkv_ + l * 384;
    const float* bo = bo_ + l * 128;
    const float* b1 = b1_ + l * 512;
    const float* b2 = b2_ + l * 128;
    const float* g1 = g1_ + l * 128;
    const float* be1 = be1_ + l * 128;
    const float* g2 = g2_ + l * 128;
    const float* be2 = be2_ + l * 128;

    // qkv = x @ Wqkv.T + bqkv   (w loads coalesced on o)
    for (int o = tid; o < 3 * EDIM; o += 256) {
      const float* wc = WqkvT + o;
      float bias = bqkv[o];
      float acc[SEQ];
#pragma unroll
      for (int t = 0; t < SEQ; ++t) acc[t] = bias;
#pragma unroll 2
      for (int e = 0; e < EDIM; e += 8) {
        float w0 = wc[(e + 0) * 384], w1 = wc[(e + 1) * 384];
        float w2 = wc[(e + 2) * 384], w3 = wc[(e + 3) * 384];
        float w4 = wc[(e + 4) * 384], w5 = wc[(e + 5) * 384];
        float w6 = wc[(e + 6) * 384], w7 = wc[(e + 7) * 384];
#pragma unroll
        for (int t = 0; t < SEQ; ++t) {
          float4 x0 = *(const float4*)&xs[t][e];
          float4 x1 = *(const float4*)&xs[t][e + 4];
          acc[t] += w0 * x0.x + w1 * x0.y + w2 * x0.z + w3 * x0.w +
                    w4 * x1.x + w5 * x1.y + w6 * x1.z + w7 * x1.w;
        }
      }
#pragma unroll
      for (int t = 0; t < SEQ; ++t) qkvs[t][o] = acc[t];
    }
    __syncthreads();

    // attention: 96 threads, one (head, query-token) each; Dh=16, scale=0.25
    if (tid < NHEAD * SEQ) {
      int h = tid % NHEAD, tq = tid / NHEAD;
      const float scale = 0.25f;
      float s[SEQ];
      float mx = -1e30f;
#pragma unroll
      for (int tk = 0; tk < SEQ; ++tk) {
        float d = 0.f;
#pragma unroll
        for (int dd = 0; dd < 16; ++dd)
          d += qkvs[tq][h * 16 + dd] * qkvs[tk][EDIM + h * 16 + dd];
        s[tk] = d * scale;
        mx = fmaxf(mx, s[tk]);
      }
      float sum = 0.f;
#pragma unroll
      for (int tk = 0; tk < SEQ; ++tk) {
        s[tk] = __expf(s[tk] - mx);
        sum += s[tk];
      }
      float inv = 1.0f / sum;
#pragma unroll
      for (int dd = 0; dd < 16; ++dd) {
        float o = 0.f;
#pragma unroll
        for (int tk = 0; tk < SEQ; ++tk)
          o += s[tk] * qkvs[tk][2 * EDIM + h * 16 + dd];
        atto[tq][h * 16 + dd] = o * inv;
      }
    }
    __syncthreads();

    // out-proj + residual  (WoT[i*128+e]: coalesced on e)
    {
      int e = tid % EDIM, half = tid / EDIM;
      float acc[6];
#pragma unroll
      for (int t = 0; t < 6; ++t) acc[t] = bo[e];
#pragma unroll 2
      for (int i = 0; i < EDIM; i += 8) {
        float w0 = WoT[(i + 0) * 128 + e], w1 = WoT[(i + 1) * 128 + e];
        float w2 = WoT[(i + 2) * 128 + e], w3 = WoT[(i + 3) * 128 + e];
        float w4 = WoT[(i + 4) * 128 + e], w5 = WoT[(i + 5) * 128 + e];
        float w6 = WoT[(i + 6) * 128 + e], w7 = WoT[(i + 7) * 128 + e];
#pragma unroll
        for (int t = 0; t < 6; ++t) {
          int tt = half * 6 + t;
          float4 a0 = *(const float4*)&atto[tt][i];
          float4 a1 = *(const float4*)&atto[tt][i + 4];
          acc[t] += w0 * a0.x + w1 * a0.y + w2 * a0.z + w3 * a0.w +
                    w4 * a1.x + w5 * a1.y + w6 * a1.z + w7 * a1.w;
        }
      }
#pragma unroll
      for (int t = 0; t < 6; ++t) {
        int tt = half * 6 + t;
        rbuf[tt][e] = xs[tt][e] + acc[t];
      }
    }
    __syncthreads();
    ln_block(rbuf, xs, g1, be1, tid);
    __syncthreads();

    // FFN1 (relu)  (W1T[e*512+f]: coalesced on f)
    for (int f = tid; f < FDIM; f += 256) {
      const float* wc = W1T + f;
      float bias = b1[f];
      float acc[SEQ];
#pragma unroll
      for (int t = 0; t < SEQ; ++t) acc[t] = bias;
#pragma unroll 2
      for (int e = 0; e < EDIM; e += 8) {
        float w0 = wc[(e + 0) * 512], w1 = wc[(e + 1) * 512];
        float w2 = wc[(e + 2) * 512], w3 = wc[(e + 3) * 512];
        float w4 = wc[(e + 4) * 512], w5 = wc[(e + 5) * 512];
        float w6 = wc[(e + 6) * 512], w7 = wc[(e + 7) * 512];
#pragma unroll
        for (int t = 0; t < SEQ; ++t) {
          float4 x0 = *(const float4*)&xs[t][e];
          float4 x1 = *(const float4*)&xs[t][e + 4];
          acc[t] += w0 * x0.x + w1 * x0.y + w2 * x0.z + w3 * x0.w +
                    w4 * x1.x + w5 * x1.y + w6 * x1.z + w7 * x1.w;
        }
      }
#pragma unroll
      for (int t = 0; t < SEQ; ++t) h1s[t][f] = fmaxf(acc[t], 0.0f);
    }
    __syncthreads();

    // FFN2 + residual  (W2T[f*128+e]: coalesced on e)
    {
      int e = tid % EDIM, half = tid / EDIM;
      float acc[6];
#pragma unroll
      for (int t = 0; t < 6; ++t) acc[t] = b2[e];
#pragma unroll 2
      for (int f = 0; f < FDIM; f += 8) {
        float w0 = W2T[(f + 0) * 128 + e], w1 = W2T[(f + 1) * 128 + e];
        float w2 = W2T[(f + 2) * 128 + e], w3 = W2T[(f + 3) * 128 + e];
        float w4 = W2T[(f + 4) * 128 + e], w5 = W2T[(f + 5) * 128 + e];
        float w6 = W2T[(f + 6) * 128 + e], w7 = W2T[(f + 7) * 128 + e];
#pragma unroll
        for (int t = 0; t < 6; ++t) {
          int tt = half * 6 + t;
          float4 h0 = *(const float4*)&h1s[tt][f];
          float4 h1 = *(const float4*)&h1s[tt][f + 4];
          acc[t] += w0 * h0.x + w1 * h0.y + w2 * h0.z + w3 * h0.w +
                    w4 * h1.x + w5 * h1.y + w6 * h1.z + w7 * h1.w;
        }
      }
#pragma unroll
      for (int t = 0; t < 6; ++t) {
        int tt = half * 6 + t;
        rbuf[tt][e] = xs[tt][e] + acc[t];
      }
    }
    __syncthreads();
    ln_block(rbuf, xs, g2, be2, tid);
    __syncthreads();
  }

  // ---- prep epilogue: swizzled Abfs (R2 layout: halfwise, key b&7) ----
  if (tid < EDIM) {
    int e = tid;
    int r = nextCheckin[1 * NB + b];
    float a0 = xs[0][e] * rel[(size_t)r * EDIM + e];
    float a1 = xs[1][e] * rel_inv[(size_t)r * EDIM + e];
    int c = e >> 3, j = e & 7, s = b & 7;
    Abfs[b * 256 + ((c ^ s) << 3) + j] = f2bf(a0);
    Abfs[b * 256 + 128 + ((c ^ s) << 3) + j] = f2bf(a1);
    hist[(size_t)b * EDIM + e] = xs[11][e];
  }
}

// ---------------- scores: bf16 MFMA GEMM (round-2 structure + bfr hoist) ---
// M=512 N=100000 K=256. One block per 64-col N-strip (1563 blocks). B staged
// once fp32->bf16 into swizzled LDS, fragments hoisted to 32 VGPRs; A
// streamed through LDS in 8 chunks of 64 rows via global_load_lds w16 from
// the pre-swizzled Abfs. Two barriers per chunk (known-good 115us baseline).
__global__ __launch_bounds__(256) void score_kernel(
    const short* __restrict__ Abfs, const float* __restrict__ ent,
    const float* __restrict__ ent_t, float* __restrict__ out) {
  __shared__ char lds[65536];
  char* Asb = lds;           // 32 KB: A chunk [64][256] bf16, swizzled
  char* Bsb = lds + 32768;   // 32 KB: B strip [64][256] bf16, swizzled

  int tid = threadIdx.x;
  int wave = tid >> 6;
  int lane = tid & 63;
  int nbase = blockIdx.x * 64;

  // ---- stage B strip: 64 rows x 256 k fp32 -> bf16, swizzled ds_write ----
#pragma unroll
  for (int i = 0; i < 16; ++i) {
    int flat = i * 256 + tid;  // 0..4095 float4 slots
    int row = flat >> 6;       // 0..63
    int c4 = flat & 63;        // float4 index within row (k = c4*4)
    int n = nbase + row;
    float4 v = make_float4(0.f, 0.f, 0.f, 0.f);
    if (n < N_ENT) {
      const float* src = (c4 < 32) ? ent + (size_t)n * 128 + c4 * 4
                                   : ent_t + (size_t)n * 128 + (c4 - 32) * 4;
      v = *(const float4*)src;
    }
    short4 bb;
    bb.x = f2bf(v.x); bb.y = f2bf(v.y); bb.z = f2bf(v.z); bb.w = f2bf(v.w);
    int chunk = c4 >> 1, half = c4 & 1;
    *(short4*)(Bsb + row * 512 + ((chunk ^ (row & 7)) << 4) + half * 8) = bb;
  }
  __syncthreads();  // B visible

  int q = lane >> 4;   // 0..3 (k-quarter)
  int lr = lane & 15;
  int rb = wave * 16 + lr;               // B lds row for this wave
  int col = nbase + rb;                  // output column
  bool cvalid = (col < N_ENT);

  // hoist B fragments for all 8 k-steps into registers
  bf16x8 bfr[8];
#pragma unroll
  for (int ks = 0; ks < 8; ++ks) {
    int cg = ks * 4 + q;
    bfr[ks] = *(const bf16x8*)(Bsb + rb * 512 + ((cg ^ (rb & 7)) << 4));
  }

  const char* gA = (const char*)Abfs;
  f32x4 acc[4];

  for (int mc = 0; mc < 8; ++mc) {
    __syncthreads();  // previous chunk's LDS reads done
    // ---- stage A chunk (64 rows = 32 KB), 8 KB per wave ----
#pragma unroll
    for (int it = 0; it < 8; ++it) {
      int off = wave * 8192 + it * 1024;
      __builtin_amdgcn_global_load_lds(
          (const __attribute__((address_space(1))) uint32_t*)(
              gA + (size_t)mc * 32768 + off + lane * 16),
          (__attribute__((address_space(3))) uint32_t*)(Asb + off), 16, 0, 0);
    }
    __syncthreads();  // staging complete

#pragma unroll
    for (int mi = 0; mi < 4; ++mi)
#pragma unroll
      for (int r = 0; r < 4; ++r) acc[mi][r] = 0.0f;

#pragma unroll
    for (int ks = 0; ks < 8; ++ks) {
      int cg = ks * 4 + q;
#pragma unroll
      for (int mi = 0; mi < 4; ++mi) {
        int ra = mi * 16 + lr;
        bf16x8 afrag = *(const bf16x8*)(Asb + ra * 512 + ((cg ^ (ra & 7)) << 4));
        acc[mi] = __builtin_amdgcn_mfma_f32_16x16x32_bf16(afrag, bfr[ks], acc[mi], 0, 0, 0);
      }
    }

    if (cvalid) {
#pragma unroll
      for (int mi = 0; mi < 4; ++mi) {
        int mrow = mc * 64 + mi * 16 + q * 4;
#pragma unroll
        for (int r = 0; r < 4; ++r) {
          float v = acc[mi][r] * 0.5f;
          v = fminf(fmaxf(v, -20.0f), 20.0f);
          out[(size_t)(mrow + r) * N_ENT + col] = v;
        }
      }
    }
  }
}

extern "C" void kernel_launch(void* const* d_in, const int* in_sizes, int n_in,
                              void* d_out, int out_size, void* d_ws,
                              size_t ws_size, hipStream_t stream) {
  const int* inp = (const int*)d_in[0];
  const int* nextCheckin = (const int*)d_in[1];
  const float* ctxSub = (const float*)d_in[2];
  const float* ent = (const float*)d_in[3];
  const float* ent_t = (const float*)d_in[4];
  const float* rel = (const float*)d_in[5];
  const float* rel_inv = (const float*)d_in[6];
  const float* ctx = (const float*)d_in[7];
  const float* Wqkv = (const float*)d_in[8];
  const float* bqkv = (const float*)d_in[9];
  const float* Wo = (const float*)d_in[10];
  const float* bo = (const float*)d_in[11];
  const float* W1 = (const float*)d_in[12];
  const float* b1 = (const float*)d_in[13];
  const float* W2 = (const float*)d_in[14];
  const float* b2 = (const float*)d_in[15];
  const float* g1 = (const float*)d_in[16];
  const float* be1 = (const float*)d_in[17];
  const float* g2 = (const float*)d_in[18];
  const float* be2 = (const float*)d_in[19];
  float* out = (float*)d_out;

  short* Abfs = (short*)d_ws;                         // 256 KB
  float* WT = (float*)((char*)d_ws + 262144);         // 1.5 MB
  float* hist = out + (size_t)NB * N_ENT;

  wt_kernel<<<1536, 256, 0, stream>>>(Wqkv, Wo, W1, W2, WT);
  encoder_fused<<<NB, 256, 0, stream>>>(
      inp, nextCheckin, ctxSub, ent, ent_t, rel, rel_inv, ctx, WT, bqkv, bo,
      b1, b2, g1, be1, g2, be2, Abfs, hist);
  score_kernel<<<1563, 256, 0, stream>>>(Abfs, ent, ent_t, out);
}

// Round 11
// 157.430 us; speedup vs baseline: 2.4470x; 1.7787x over previous
//
#include <hip/hip_runtime.h>
#include <hip/hip_bf16.h>
#include <stdint.h>

#define N_ENT 100000
#define EDIM 128
#define NHEAD 8
#define FDIM 512
#define NB 512
#define SEQ 12
#define CTXL 5
#define LN_EPS 1e-5f
#define QS 388  // qkvf row stride (floats): 384+4 pad spreads banks
#define RS 132  // rbuf row stride (floats)

typedef __attribute__((ext_vector_type(8))) short bf16x8;
typedef __attribute__((ext_vector_type(4))) float f32x4;

__device__ __forceinline__ short f2bf(float f) {
  __hip_bfloat16 h = __float2bfloat16(f);
  return (short)__bfloat16_as_ushort(h);
}
__device__ __forceinline__ float bf2f(unsigned short u) {
  union { uint32_t i; float f; } x; x.i = ((uint32_t)u) << 16; return x.f;
}

// swizzled byte addr inside bf16 LDS tiles (16B chunks XOR row&7)
__device__ __forceinline__ int XADDR(int row, int k) {  // stride 256B (128 bf16)
  return row * 256 + ((((k) >> 3) ^ (row & 7)) << 4) + ((k) & 7) * 2;
}
__device__ __forceinline__ int AADDR(int row, int k) {  // stride 1024B (512 bf16)
  return row * 1024 + ((((k) >> 3) ^ (row & 7)) << 4) + ((k) & 7) * 2;
}

// ---- weights -> bf16, native [out][in] layouts, per-layer contiguous ----
// per layer: Wq 384x128 @0 | Wo 128x128 @49152 | W1 512x128 @65536 | W2 128x512 @131072
#define LSTRIDE 196608
__global__ void wbf_kernel(const float* __restrict__ Wqkv,
                           const float* __restrict__ Wo,
                           const float* __restrict__ W1,
                           const float* __restrict__ W2,
                           short* __restrict__ Wbf) {
  int idx = blockIdx.x * 256 + threadIdx.x;  // 0..393215
  int layer = idx / LSTRIDE;
  int r = idx % LSTRIDE;
  float v;
  if (r < 49152) v = Wqkv[layer * 49152 + r];
  else if (r < 65536) v = Wo[layer * 16384 + (r - 49152)];
  else if (r < 131072) v = W1[layer * 65536 + (r - 65536)];
  else v = W2[layer * 65536 + (r - 131072)];
  Wbf[idx] = f2bf(v);
}

// ------- fused MFMA encoder: gather -> 2 layers -> prep (Abfs + hist) ------
// One block per 2 batch elems (256 blocks). M=24 tokens (pad 32, 2 M-tiles).
// GEMMs on mfma_16x16x32_bf16: A = swizzled bf16 LDS, B = bf16 weights from
// global (L2-resident). Epilogues fp32 (bias/residual/relu) -> rbuf; LN via
// shfl. LDS 78.2KB -> 2 blocks/CU.
__global__ __launch_bounds__(256, 2) void encoder_fused(
    const int* __restrict__ inp, const int* __restrict__ nextCheckin,
    const float* __restrict__ ctxSub, const float* __restrict__ ent,
    const float* __restrict__ ent_t, const float* __restrict__ rel,
    const float* __restrict__ rel_inv, const float* __restrict__ ctx,
    const short* __restrict__ Wbf, const float* __restrict__ bqkv_,
    const float* __restrict__ bo_, const float* __restrict__ b1_,
    const float* __restrict__ b2_, const float* __restrict__ g1_,
    const float* __restrict__ be1_, const float* __restrict__ g2_,
    const float* __restrict__ be2_, short* __restrict__ Abfs,
    float* __restrict__ hist) {
  __shared__ char lds[78208];
  char* xbuf = lds;                          // [32][128] bf16 swz   8KB
  char* abuf = lds + 8192;                   // [32][512] bf16 swz  32KB
  float* qkvf = (float*)(lds + 40960);       // [24][388] fp32      37.25KB
  float* rbuf = (float*)(lds + 40960);       // [24][132] fp32 (reuse)

  int b2 = blockIdx.x;
  int tid = threadIdx.x;
  int wave = tid >> 6, lane = tid & 63;
  int q = lane >> 4, lr = lane & 15;

  // ---- gather -> xbuf bf16 (swizzled); zero pad rows of xbuf/abuf ----
  {
    for (int i = tid; i < 512; i += 256) ((uint32_t*)(xbuf + 24 * 256))[i] = 0;
    for (int i = tid; i < 2048; i += 256) ((uint32_t*)(abuf + 24 * 1024))[i] = 0;
    int bl = tid >> 7, e = tid & 127;
    int m = 2 * b2 + bl;
    int i0 = inp[0 * NB + m], i1 = inp[1 * NB + m], i2 = inp[2 * NB + m];
    int row = bl * 12;
    *(unsigned short*)(xbuf + XADDR(row + 0, e)) = (unsigned short)f2bf(ent[(size_t)i0 * EDIM + e]);
    *(unsigned short*)(xbuf + XADDR(row + 1, e)) = (unsigned short)f2bf(ent_t[(size_t)i0 * EDIM + e]);
    *(unsigned short*)(xbuf + XADDR(row + 2, e)) = (unsigned short)f2bf(rel[(size_t)i1 * EDIM + e]);
    *(unsigned short*)(xbuf + XADDR(row + 3, e)) = (unsigned short)f2bf(rel_inv[(size_t)i1 * EDIM + e]);
    *(unsigned short*)(xbuf + XADDR(row + 4, e)) = (unsigned short)f2bf(ent[(size_t)i2 * EDIM + e]);
    *(unsigned short*)(xbuf + XADDR(row + 5, e)) = (unsigned short)f2bf(ent_t[(size_t)i2 * EDIM + e]);
#pragma unroll
    for (int j = 0; j < CTXL; ++j) {
      int c = inp[(3 + j) * NB + m];
      *(unsigned short*)(xbuf + XADDR(row + 6 + j, e)) = (unsigned short)f2bf(ctx[(size_t)c * EDIM + e]);
    }
    *(unsigned short*)(xbuf + XADDR(row + 11, e)) = (unsigned short)f2bf(ctxSub[(size_t)m * EDIM + e]);
  }
  __syncthreads();

  for (int l = 0; l < 2; ++l) {
    const short* Wq = Wbf + (size_t)l * LSTRIDE;
    const short* Wo = Wq + 49152;
    const short* W1 = Wq + 65536;
    const short* W2 = Wq + 131072;
    const float* bqkv = bqkv_ + l * 384;
    const float* bo = bo_ + l * 128;
    const float* b1 = b1_ + l * 512;
    const float* b2 = b2_ + l * 128;
    const float* g1 = g1_ + l * 128;
    const float* be1 = be1_ + l * 128;
    const float* g2 = g2_ + l * 128;
    const float* be2 = be2_ + l * 128;

    // ---------- qkv GEMM: qkvf[t][o] = x @ Wq^T + bqkv ----------
    {
      bf16x8 a[2][4];
#pragma unroll
      for (int mt = 0; mt < 2; ++mt)
#pragma unroll
        for (int ks = 0; ks < 4; ++ks)
          a[mt][ks] = *(const bf16x8*)(xbuf + XADDR(mt * 16 + lr, ks * 32 + q * 8) - ((ks * 32 + q * 8) & 7) * 2);
      for (int nt = wave; nt < 24; nt += 4) {
        const short* wr = Wq + (nt * 16 + lr) * 128;
        bf16x8 bq[4];
#pragma unroll
        for (int ks = 0; ks < 4; ++ks) bq[ks] = *(const bf16x8*)(wr + ks * 32 + q * 8);
        float bias = bqkv[nt * 16 + lr];
#pragma unroll
        for (int mt = 0; mt < 2; ++mt) {
          f32x4 acc{};
#pragma unroll
          for (int ks = 0; ks < 4; ++ks)
            acc = __builtin_amdgcn_mfma_f32_16x16x32_bf16(a[mt][ks], bq[ks], acc, 0, 0, 0);
          int tbase = mt * 16 + q * 4;
          if (tbase < 24) {
#pragma unroll
            for (int r = 0; r < 4; ++r)
              qkvf[(tbase + r) * QS + nt * 16 + lr] = acc[r] + bias;
          }
        }
      }
    }
    __syncthreads();

    // ---------- attention (192 threads, fp32 from qkvf) ----------
    if (tid < 192) {
      int bl = tid / 96, rr = tid % 96, h = rr & 7, tq = rr >> 3;
      int trow = bl * 12 + tq;
      const float scale = 0.25f;
      float s[SEQ];
      float mx = -1e30f;
#pragma unroll
      for (int tk = 0; tk < SEQ; ++tk) {
        float d = 0.f;
#pragma unroll
        for (int dd = 0; dd < 16; ++dd)
          d += qkvf[trow * QS + h * 16 + dd] * qkvf[(bl * 12 + tk) * QS + 128 + h * 16 + dd];
        s[tk] = d * scale;
        mx = fmaxf(mx, s[tk]);
      }
      float sum = 0.f;
#pragma unroll
      for (int tk = 0; tk < SEQ; ++tk) { s[tk] = __expf(s[tk] - mx); sum += s[tk]; }
      float inv = 1.0f / sum;
#pragma unroll
      for (int dd = 0; dd < 16; dd += 2) {
        float o0 = 0.f, o1 = 0.f;
#pragma unroll
        for (int tk = 0; tk < SEQ; ++tk) {
          o0 += s[tk] * qkvf[(bl * 12 + tk) * QS + 256 + h * 16 + dd];
          o1 += s[tk] * qkvf[(bl * 12 + tk) * QS + 256 + h * 16 + dd + 1];
        }
        uint32_t pk = (uint32_t)(unsigned short)f2bf(o0 * inv) |
                      ((uint32_t)(unsigned short)f2bf(o1 * inv) << 16);
        *(uint32_t*)(abuf + AADDR(trow, h * 16 + dd)) = pk;
      }
    }
    __syncthreads();

    // ---------- out-proj GEMM + residual -> rbuf ----------
    {
      bf16x8 a[2][4];
#pragma unroll
      for (int mt = 0; mt < 2; ++mt)
#pragma unroll
        for (int ks = 0; ks < 4; ++ks)
          a[mt][ks] = *(const bf16x8*)(abuf + AADDR(mt * 16 + lr, ks * 32 + q * 8));
      for (int nt = wave; nt < 8; nt += 4) {
        const short* wr = Wo + (nt * 16 + lr) * 128;
        bf16x8 bq[4];
#pragma unroll
        for (int ks = 0; ks < 4; ++ks) bq[ks] = *(const bf16x8*)(wr + ks * 32 + q * 8);
        float bias = bo[nt * 16 + lr];
#pragma unroll
        for (int mt = 0; mt < 2; ++mt) {
          f32x4 acc{};
#pragma unroll
          for (int ks = 0; ks < 4; ++ks)
            acc = __builtin_amdgcn_mfma_f32_16x16x32_bf16(a[mt][ks], bq[ks], acc, 0, 0, 0);
          int tbase = mt * 16 + q * 4;
          if (tbase < 24) {
            int e = nt * 16 + lr;
#pragma unroll
            for (int r = 0; r < 4; ++r) {
              int t = tbase + r;
              float res = bf2f(*(const unsigned short*)(xbuf + XADDR(t, e)));
              rbuf[t * RS + e] = acc[r] + bias + res;
            }
          }
        }
      }
    }
    __syncthreads();

    // ---------- LN1: rbuf -> xbuf (bf16) ----------
    {
      int wv = wave, ll = lane;
      for (int row = wv; row < 24; row += 4) {
        float v0 = rbuf[row * RS + 2 * ll], v1 = rbuf[row * RS + 2 * ll + 1];
        float sum = v0 + v1, sq = v0 * v0 + v1 * v1;
#pragma unroll
        for (int off = 32; off; off >>= 1) { sum += __shfl_xor(sum, off); sq += __shfl_xor(sq, off); }
        float mu = sum * (1.0f / 128.0f);
        float var = sq * (1.0f / 128.0f) - mu * mu;
        float rs = rsqrtf(var + LN_EPS);
        float y0 = (v0 - mu) * rs * g1[2 * ll] + be1[2 * ll];
        float y1 = (v1 - mu) * rs * g1[2 * ll + 1] + be1[2 * ll + 1];
        uint32_t pk = (uint32_t)(unsigned short)f2bf(y0) |
                      ((uint32_t)(unsigned short)f2bf(y1) << 16);
        *(uint32_t*)(xbuf + XADDR(row, 2 * ll)) = pk;
      }
    }
    __syncthreads();

    // ---------- FFN1 GEMM + relu -> abuf ----------
    {
      bf16x8 a[2][4];
#pragma unroll
      for (int mt = 0; mt < 2; ++mt)
#pragma unroll
        for (int ks = 0; ks < 4; ++ks)
          a[mt][ks] = *(const bf16x8*)(xbuf + XADDR(mt * 16 + lr, ks * 32 + q * 8) - ((ks * 32 + q * 8) & 7) * 2);
      for (int nt = wave; nt < 32; nt += 4) {
        const short* wr = W1 + (nt * 16 + lr) * 128;
        bf16x8 bq[4];
#pragma unroll
        for (int ks = 0; ks < 4; ++ks) bq[ks] = *(const bf16x8*)(wr + ks * 32 + q * 8);
        float bias = b1[nt * 16 + lr];
#pragma unroll
        for (int mt = 0; mt < 2; ++mt) {
          f32x4 acc{};
#pragma unroll
          for (int ks = 0; ks < 4; ++ks)
            acc = __builtin_amdgcn_mfma_f32_16x16x32_bf16(a[mt][ks], bq[ks], acc, 0, 0, 0);
          int tbase = mt * 16 + q * 4;
          if (tbase < 24) {
            int f = nt * 16 + lr;
#pragma unroll
            for (int r = 0; r < 4; ++r) {
              float h = fmaxf(acc[r] + bias, 0.0f);
              *(unsigned short*)(abuf + AADDR(tbase + r, f)) = (unsigned short)f2bf(h);
            }
          }
        }
      }
    }
    __syncthreads();

    // ---------- FFN2 GEMM (K=512) + residual -> rbuf ----------
    {
#pragma unroll
      for (int mt = 0; mt < 2; ++mt) {
        bf16x8 a2[16];
#pragma unroll
        for (int ks = 0; ks < 16; ++ks)
          a2[ks] = *(const bf16x8*)(abuf + AADDR(mt * 16 + lr, ks * 32 + q * 8));
        for (int nt = wave; nt < 8; nt += 4) {
          const short* wr = W2 + (nt * 16 + lr) * 512;
          float bias = b2[nt * 16 + lr];
          f32x4 acc{};
#pragma unroll
          for (int ks = 0; ks < 16; ++ks) {
            bf16x8 bq = *(const bf16x8*)(wr + ks * 32 + q * 8);
            acc = __builtin_amdgcn_mfma_f32_16x16x32_bf16(a2[ks], bq, acc, 0, 0, 0);
          }
          int tbase = mt * 16 + q * 4;
          if (tbase < 24) {
            int e = nt * 16 + lr;
#pragma unroll
            for (int r = 0; r < 4; ++r) {
              int t = tbase + r;
              float res = bf2f(*(const unsigned short*)(xbuf + XADDR(t, e)));
              rbuf[t * RS + e] = acc[r] + bias + res;
            }
          }
        }
      }
    }
    __syncthreads();

    // ---------- LN2: rbuf -> xbuf (bf16) + rbuf (fp32, for epilogue) ------
    {
      int wv = wave, ll = lane;
      for (int row = wv; row < 24; row += 4) {
        float v0 = rbuf[row * RS + 2 * ll], v1 = rbuf[row * RS + 2 * ll + 1];
        float sum = v0 + v1, sq = v0 * v0 + v1 * v1;
#pragma unroll
        for (int off = 32; off; off >>= 1) { sum += __shfl_xor(sum, off); sq += __shfl_xor(sq, off); }
        float mu = sum * (1.0f / 128.0f);
        float var = sq * (1.0f / 128.0f) - mu * mu;
        float rs = rsqrtf(var + LN_EPS);
        float y0 = (v0 - mu) * rs * g2[2 * ll] + be2[2 * ll];
        float y1 = (v1 - mu) * rs * g2[2 * ll + 1] + be2[2 * ll + 1];
        uint32_t pk = (uint32_t)(unsigned short)f2bf(y0) |
                      ((uint32_t)(unsigned short)f2bf(y1) << 16);
        *(uint32_t*)(xbuf + XADDR(row, 2 * ll)) = pk;
        rbuf[row * RS + 2 * ll] = y0;
        rbuf[row * RS + 2 * ll + 1] = y1;
      }
    }
    __syncthreads();
  }

  // ---- prep epilogue: swizzled Abfs + hist from fp32 rbuf ----
  {
    int bl = tid >> 7, e = tid & 127;
    int m = 2 * b2 + bl;
    int r = nextCheckin[NB + m];
    float a0 = rbuf[(bl * 12 + 0) * RS + e] * rel[(size_t)r * EDIM + e];
    float a1 = rbuf[(bl * 12 + 1) * RS + e] * rel_inv[(size_t)r * EDIM + e];
    int s = m & 7, c = e >> 3, j = e & 7;
    Abfs[m * 256 + ((c ^ s) << 3) + j] = f2bf(a0);
    Abfs[m * 256 + 128 + ((c ^ s) << 3) + j] = f2bf(a1);
    hist[(size_t)m * EDIM + e] = rbuf[(bl * 12 + 11) * RS + e];
  }
}

// ---------------- scores: bf16 MFMA GEMM (round-9, unchanged) --------------
__global__ __launch_bounds__(256) void score_kernel(
    const short* __restrict__ Abfs, const float* __restrict__ ent,
    const float* __restrict__ ent_t, float* __restrict__ out) {
  __shared__ char lds[65536];
  char* Asb = lds;
  char* Bsb = lds + 32768;

  int tid = threadIdx.x;
  int wave = tid >> 6;
  int lane = tid & 63;
  int nbase = blockIdx.x * 64;

#pragma unroll
  for (int i = 0; i < 16; ++i) {
    int flat = i * 256 + tid;
    int row = flat >> 6;
    int c4 = flat & 63;
    int n = nbase + row;
    float4 v = make_float4(0.f, 0.f, 0.f, 0.f);
    if (n < N_ENT) {
      const float* src = (c4 < 32) ? ent + (size_t)n * 128 + c4 * 4
                                   : ent_t + (size_t)n * 128 + (c4 - 32) * 4;
      v = *(const float4*)src;
    }
    short4 bb;
    bb.x = f2bf(v.x); bb.y = f2bf(v.y); bb.z = f2bf(v.z); bb.w = f2bf(v.w);
    int chunk = c4 >> 1, half = c4 & 1;
    *(short4*)(Bsb + row * 512 + ((chunk ^ (row & 7)) << 4) + half * 8) = bb;
  }
  __syncthreads();

  int q = lane >> 4;
  int lr = lane & 15;
  int rb = wave * 16 + lr;
  int col = nbase + rb;
  bool cvalid = (col < N_ENT);

  bf16x8 bfr[8];
#pragma unroll
  for (int ks = 0; ks < 8; ++ks) {
    int cg = ks * 4 + q;
    bfr[ks] = *(const bf16x8*)(Bsb + rb * 512 + ((cg ^ (rb & 7)) << 4));
  }

  const char* gA = (const char*)Abfs;
  f32x4 acc[4];

  for (int mc = 0; mc < 8; ++mc) {
    __syncthreads();
#pragma unroll
    for (int it = 0; it < 8; ++it) {
      int off = wave * 8192 + it * 1024;
      __builtin_amdgcn_global_load_lds(
          (const __attribute__((address_space(1))) uint32_t*)(
              gA + (size_t)mc * 32768 + off + lane * 16),
          (__attribute__((address_space(3))) uint32_t*)(Asb + off), 16, 0, 0);
    }
    __syncthreads();

#pragma unroll
    for (int mi = 0; mi < 4; ++mi)
#pragma unroll
      for (int r = 0; r < 4; ++r) acc[mi][r] = 0.0f;

#pragma unroll
    for (int ks = 0; ks < 8; ++ks) {
      int cg = ks * 4 + q;
#pragma unroll
      for (int mi = 0; mi < 4; ++mi) {
        int ra = mi * 16 + lr;
        bf16x8 afrag = *(const bf16x8*)(Asb + ra * 512 + ((cg ^ (ra & 7)) << 4));
        acc[mi] = __builtin_amdgcn_mfma_f32_16x16x32_bf16(afrag, bfr[ks], acc[mi], 0, 0, 0);
      }
    }

    if (cvalid) {
#pragma unroll
      for (int mi = 0; mi < 4; ++mi) {
        int mrow = mc * 64 + mi * 16 + q * 4;
#pragma unroll
        for (int r = 0; r < 4; ++r) {
          float v = acc[mi][r] * 0.5f;
          v = fminf(fmaxf(v, -20.0f), 20.0f);
          out[(size_t)(mrow + r) * N_ENT + col] = v;
        }
      }
    }
  }
}

extern "C" void kernel_launch(void* const* d_in, const int* in_sizes, int n_in,
                              void* d_out, int out_size, void* d_ws,
                              size_t ws_size, hipStream_t stream) {
  const int* inp = (const int*)d_in[0];
  const int* nextCheckin = (const int*)d_in[1];
  const float* ctxSub = (const float*)d_in[2];
  const float* ent = (const float*)d_in[3];
  const float* ent_t = (const float*)d_in[4];
  const float* rel = (const float*)d_in[5];
  const float* rel_inv = (const float*)d_in[6];
  const float* ctx = (const float*)d_in[7];
  const float* Wqkv = (const float*)d_in[8];
  const float* bqkv = (const float*)d_in[9];
  const float* Wo = (const float*)d_in[10];
  const float* bo = (const float*)d_in[11];
  const float* W1 = (const float*)d_in[12];
  const float* b1 = (const float*)d_in[13];
  const float* W2 = (const float*)d_in[14];
  const float* b2 = (const float*)d_in[15];
  const float* g1 = (const float*)d_in[16];
  const float* be1 = (const float*)d_in[17];
  const float* g2 = (const float*)d_in[18];
  const float* be2 = (const float*)d_in[19];
  float* out = (float*)d_out;

  short* Abfs = (short*)d_ws;                         // 256 KB
  short* Wbf = (short*)((char*)d_ws + 262144);        // 768 KB bf16 weights
  float* hist = out + (size_t)NB * N_ENT;

  wbf_kernel<<<1536, 256, 0, stream>>>(Wqkv, Wo, W1, W2, Wbf);
  encoder_fused<<<256, 256, 0, stream>>>(
      inp, nextCheckin, ctxSub, ent, ent_t, rel, rel_inv, ctx, Wbf, bqkv, bo,
      b1, b2, g1, be1, g2, be2, Abfs, hist);
  score_kernel<<<1563, 256, 0, stream>>>(Abfs, ent, ent_t, out);
}

// Round 12
// 154.250 us; speedup vs baseline: 2.4975x; 1.0206x over previous
//
#include <hip/hip_runtime.h>
#include <hip/hip_bf16.h>
#include <stdint.h>

#define N_ENT 100000
#define EDIM 128
#define NHEAD 8
#define FDIM 512
#define NB 512
#define SEQ 12
#define CTXL 5
#define LN_EPS 1e-5f
#define QS 388  // qkvf row stride (floats): 384+4 pad spreads banks
#define RS 132  // rbuf row stride (floats)

typedef __attribute__((ext_vector_type(8))) short bf16x8;
typedef __attribute__((ext_vector_type(4))) float f32x4;

__device__ __forceinline__ short f2bf(float f) {
  __hip_bfloat16 h = __float2bfloat16(f);
  return (short)__bfloat16_as_ushort(h);
}
__device__ __forceinline__ float bf2f(unsigned short u) {
  union { uint32_t i; float f; } x; x.i = ((uint32_t)u) << 16; return x.f;
}

// swizzled byte addr inside bf16 LDS tiles (16B chunks XOR row&7)
__device__ __forceinline__ int XADDR(int row, int k) {  // stride 256B (128 bf16)
  return row * 256 + ((((k) >> 3) ^ (row & 7)) << 4) + ((k) & 7) * 2;
}
__device__ __forceinline__ int AADDR(int row, int k) {  // stride 1024B (512 bf16)
  return row * 1024 + ((((k) >> 3) ^ (row & 7)) << 4) + ((k) & 7) * 2;
}

// ---- weights -> bf16, native [out][in] layouts, per-layer contiguous ----
#define LSTRIDE 196608
__global__ void wbf_kernel(const float* __restrict__ Wqkv,
                           const float* __restrict__ Wo,
                           const float* __restrict__ W1,
                           const float* __restrict__ W2,
                           short* __restrict__ Wbf) {
  int idx = blockIdx.x * 256 + threadIdx.x;  // 0..393215
  int layer = idx / LSTRIDE;
  int r = idx % LSTRIDE;
  float v;
  if (r < 49152) v = Wqkv[layer * 49152 + r];
  else if (r < 65536) v = Wo[layer * 16384 + (r - 49152)];
  else if (r < 131072) v = W1[layer * 65536 + (r - 65536)];
  else v = W2[layer * 65536 + (r - 131072)];
  Wbf[idx] = f2bf(v);
}

// ------- fused MFMA encoder: gather -> 2 layers -> prep (Abfs + hist) ------
// One block per batch elem (512 blocks; LDS 39KB -> 2 resident blocks/CU for
// wave-level latency hiding, 2x round-11's 1 wave/SIMD). M=12 tokens padded
// to 16 (single M-tile). GEMMs on mfma_16x16x32_bf16: A = swizzled bf16 LDS,
// B = bf16 weights streamed from global (L2-resident). Epilogues fp32.
__global__ __launch_bounds__(256, 2) void encoder_fused(
    const int* __restrict__ inp, const int* __restrict__ nextCheckin,
    const float* __restrict__ ctxSub, const float* __restrict__ ent,
    const float* __restrict__ ent_t, const float* __restrict__ rel,
    const float* __restrict__ rel_inv, const float* __restrict__ ctx,
    const short* __restrict__ Wbf, const float* __restrict__ bqkv_,
    const float* __restrict__ bo_, const float* __restrict__ b1_,
    const float* __restrict__ b2_, const float* __restrict__ g1_,
    const float* __restrict__ be1_, const float* __restrict__ g2_,
    const float* __restrict__ be2_, short* __restrict__ Abfs,
    float* __restrict__ hist) {
  __shared__ char lds[39104];
  char* xbuf = lds;                      // [16][128] bf16 swz   4KB
  char* abuf = lds + 4096;               // [16][512] bf16 swz  16KB
  float* qkvf = (float*)(lds + 20480);   // [12][388] fp32      18.2KB
  float* rbuf = (float*)(lds + 20480);   // [12][132] fp32 (reuse)

  int m = blockIdx.x;
  int tid = threadIdx.x;
  int wave = tid >> 6, lane = tid & 63;
  int q = lane >> 4, lr = lane & 15;

  // ---- gather -> xbuf bf16 (swizzled); zero pad rows 12..15 ----
  {
    for (int i = tid; i < 256; i += 256) ((uint32_t*)(xbuf + 12 * 256))[i] = 0;
    for (int i = tid; i < 1024; i += 256) ((uint32_t*)(abuf + 12 * 1024))[i] = 0;
    if (tid < EDIM) {
      int e = tid;
      int i0 = inp[0 * NB + m], i1 = inp[1 * NB + m], i2 = inp[2 * NB + m];
      *(unsigned short*)(xbuf + XADDR(0, e)) = (unsigned short)f2bf(ent[(size_t)i0 * EDIM + e]);
      *(unsigned short*)(xbuf + XADDR(1, e)) = (unsigned short)f2bf(ent_t[(size_t)i0 * EDIM + e]);
      *(unsigned short*)(xbuf + XADDR(2, e)) = (unsigned short)f2bf(rel[(size_t)i1 * EDIM + e]);
      *(unsigned short*)(xbuf + XADDR(3, e)) = (unsigned short)f2bf(rel_inv[(size_t)i1 * EDIM + e]);
      *(unsigned short*)(xbuf + XADDR(4, e)) = (unsigned short)f2bf(ent[(size_t)i2 * EDIM + e]);
      *(unsigned short*)(xbuf + XADDR(5, e)) = (unsigned short)f2bf(ent_t[(size_t)i2 * EDIM + e]);
#pragma unroll
      for (int j = 0; j < CTXL; ++j) {
        int c = inp[(3 + j) * NB + m];
        *(unsigned short*)(xbuf + XADDR(6 + j, e)) = (unsigned short)f2bf(ctx[(size_t)c * EDIM + e]);
      }
      *(unsigned short*)(xbuf + XADDR(11, e)) = (unsigned short)f2bf(ctxSub[(size_t)m * EDIM + e]);
    }
  }
  __syncthreads();

  for (int l = 0; l < 2; ++l) {
    const short* Wq = Wbf + (size_t)l * LSTRIDE;
    const short* Wo = Wq + 49152;
    const short* W1 = Wq + 65536;
    const short* W2 = Wq + 131072;
    const float* bqkv = bqkv_ + l * 384;
    const float* bo = bo_ + l * 128;
    const float* b1 = b1_ + l * 512;
    const float* b2 = b2_ + l * 128;
    const float* g1 = g1_ + l * 128;
    const float* be1 = be1_ + l * 128;
    const float* g2 = g2_ + l * 128;
    const float* be2 = be2_ + l * 128;

    // ---------- qkv GEMM: qkvf[t][o] = x @ Wq^T + bqkv ----------
    {
      bf16x8 a[4];
#pragma unroll
      for (int ks = 0; ks < 4; ++ks)
        a[ks] = *(const bf16x8*)(xbuf + XADDR(lr, ks * 32 + q * 8));
      int tbase = q * 4;
      for (int nt = wave; nt < 24; nt += 4) {
        const short* wr = Wq + (nt * 16 + lr) * 128;
        bf16x8 bq[4];
#pragma unroll
        for (int ks = 0; ks < 4; ++ks) bq[ks] = *(const bf16x8*)(wr + ks * 32 + q * 8);
        float bias = bqkv[nt * 16 + lr];
        f32x4 acc{};
#pragma unroll
        for (int ks = 0; ks < 4; ++ks)
          acc = __builtin_amdgcn_mfma_f32_16x16x32_bf16(a[ks], bq[ks], acc, 0, 0, 0);
        if (tbase < 12) {
#pragma unroll
          for (int r = 0; r < 4; ++r)
            qkvf[(tbase + r) * QS + nt * 16 + lr] = acc[r] + bias;
        }
      }
    }
    __syncthreads();

    // ---------- attention (96 threads, fp32 from qkvf) ----------
    if (tid < 96) {
      int h = tid & 7, tq = tid >> 3;
      const float scale = 0.25f;
      float s[SEQ];
      float mx = -1e30f;
#pragma unroll
      for (int tk = 0; tk < SEQ; ++tk) {
        float d = 0.f;
#pragma unroll
        for (int dd = 0; dd < 16; ++dd)
          d += qkvf[tq * QS + h * 16 + dd] * qkvf[tk * QS + 128 + h * 16 + dd];
        s[tk] = d * scale;
        mx = fmaxf(mx, s[tk]);
      }
      float sum = 0.f;
#pragma unroll
      for (int tk = 0; tk < SEQ; ++tk) { s[tk] = __expf(s[tk] - mx); sum += s[tk]; }
      float inv = 1.0f / sum;
#pragma unroll
      for (int dd = 0; dd < 16; dd += 2) {
        float o0 = 0.f, o1 = 0.f;
#pragma unroll
        for (int tk = 0; tk < SEQ; ++tk) {
          o0 += s[tk] * qkvf[tk * QS + 256 + h * 16 + dd];
          o1 += s[tk] * qkvf[tk * QS + 256 + h * 16 + dd + 1];
        }
        uint32_t pk = (uint32_t)(unsigned short)f2bf(o0 * inv) |
                      ((uint32_t)(unsigned short)f2bf(o1 * inv) << 16);
        *(uint32_t*)(abuf + AADDR(tq, h * 16 + dd)) = pk;
      }
    }
    __syncthreads();

    // ---------- out-proj GEMM + residual -> rbuf ----------
    {
      bf16x8 a[4];
#pragma unroll
      for (int ks = 0; ks < 4; ++ks)
        a[ks] = *(const bf16x8*)(abuf + AADDR(lr, ks * 32 + q * 8));
      int tbase = q * 4;
      for (int nt = wave; nt < 8; nt += 4) {
        const short* wr = Wo + (nt * 16 + lr) * 128;
        bf16x8 bq[4];
#pragma unroll
        for (int ks = 0; ks < 4; ++ks) bq[ks] = *(const bf16x8*)(wr + ks * 32 + q * 8);
        float bias = bo[nt * 16 + lr];
        f32x4 acc{};
#pragma unroll
        for (int ks = 0; ks < 4; ++ks)
          acc = __builtin_amdgcn_mfma_f32_16x16x32_bf16(a[ks], bq[ks], acc, 0, 0, 0);
        if (tbase < 12) {
          int e = nt * 16 + lr;
#pragma unroll
          for (int r = 0; r < 4; ++r) {
            int t = tbase + r;
            float res = bf2f(*(const unsigned short*)(xbuf + XADDR(t, e)));
            rbuf[t * RS + e] = acc[r] + bias + res;
          }
        }
      }
    }
    __syncthreads();

    // ---------- LN1: rbuf -> xbuf (bf16) ----------
    {
      for (int row = wave; row < SEQ; row += 4) {
        float v0 = rbuf[row * RS + 2 * lane], v1 = rbuf[row * RS + 2 * lane + 1];
        float sum = v0 + v1, sq = v0 * v0 + v1 * v1;
#pragma unroll
        for (int off = 32; off; off >>= 1) { sum += __shfl_xor(sum, off); sq += __shfl_xor(sq, off); }
        float mu = sum * (1.0f / 128.0f);
        float var = sq * (1.0f / 128.0f) - mu * mu;
        float rs = rsqrtf(var + LN_EPS);
        float y0 = (v0 - mu) * rs * g1[2 * lane] + be1[2 * lane];
        float y1 = (v1 - mu) * rs * g1[2 * lane + 1] + be1[2 * lane + 1];
        uint32_t pk = (uint32_t)(unsigned short)f2bf(y0) |
                      ((uint32_t)(unsigned short)f2bf(y1) << 16);
        *(uint32_t*)(xbuf + XADDR(row, 2 * lane)) = pk;
      }
    }
    __syncthreads();

    // ---------- FFN1 GEMM + relu -> abuf ----------
    {
      bf16x8 a[4];
#pragma unroll
      for (int ks = 0; ks < 4; ++ks)
        a[ks] = *(const bf16x8*)(xbuf + XADDR(lr, ks * 32 + q * 8));
      int tbase = q * 4;
      for (int nt = wave; nt < 32; nt += 4) {
        const short* wr = W1 + (nt * 16 + lr) * 128;
        bf16x8 bq[4];
#pragma unroll
        for (int ks = 0; ks < 4; ++ks) bq[ks] = *(const bf16x8*)(wr + ks * 32 + q * 8);
        float bias = b1[nt * 16 + lr];
        f32x4 acc{};
#pragma unroll
        for (int ks = 0; ks < 4; ++ks)
          acc = __builtin_amdgcn_mfma_f32_16x16x32_bf16(a[ks], bq[ks], acc, 0, 0, 0);
        if (tbase < 12) {
          int f = nt * 16 + lr;
#pragma unroll
          for (int r = 0; r < 4; ++r) {
            float h = fmaxf(acc[r] + bias, 0.0f);
            *(unsigned short*)(abuf + AADDR(tbase + r, f)) = (unsigned short)f2bf(h);
          }
        }
      }
    }
    __syncthreads();

    // ---------- FFN2 GEMM (K=512) + residual -> rbuf ----------
    {
      bf16x8 a2[16];
#pragma unroll
      for (int ks = 0; ks < 16; ++ks)
        a2[ks] = *(const bf16x8*)(abuf + AADDR(lr, ks * 32 + q * 8));
      int tbase = q * 4;
      for (int nt = wave; nt < 8; nt += 4) {
        const short* wr = W2 + (nt * 16 + lr) * 512;
        float bias = b2[nt * 16 + lr];
        f32x4 acc{};
#pragma unroll
        for (int ks = 0; ks < 16; ++ks) {
          bf16x8 bq = *(const bf16x8*)(wr + ks * 32 + q * 8);
          acc = __builtin_amdgcn_mfma_f32_16x16x32_bf16(a2[ks], bq, acc, 0, 0, 0);
        }
        if (tbase < 12) {
          int e = nt * 16 + lr;
#pragma unroll
          for (int r = 0; r < 4; ++r) {
            int t = tbase + r;
            float res = bf2f(*(const unsigned short*)(xbuf + XADDR(t, e)));
            rbuf[t * RS + e] = acc[r] + bias + res;
          }
        }
      }
    }
    __syncthreads();

    // ---------- LN2: rbuf -> xbuf (bf16) + rbuf (fp32) ----------
    {
      for (int row = wave; row < SEQ; row += 4) {
        float v0 = rbuf[row * RS + 2 * lane], v1 = rbuf[row * RS + 2 * lane + 1];
        float sum = v0 + v1, sq = v0 * v0 + v1 * v1;
#pragma unroll
        for (int off = 32; off; off >>= 1) { sum += __shfl_xor(sum, off); sq += __shfl_xor(sq, off); }
        float mu = sum * (1.0f / 128.0f);
        float var = sq * (1.0f / 128.0f) - mu * mu;
        float rs = rsqrtf(var + LN_EPS);
        float y0 = (v0 - mu) * rs * g2[2 * lane] + be2[2 * lane];
        float y1 = (v1 - mu) * rs * g2[2 * lane + 1] + be2[2 * lane + 1];
        uint32_t pk = (uint32_t)(unsigned short)f2bf(y0) |
                      ((uint32_t)(unsigned short)f2bf(y1) << 16);
        *(uint32_t*)(xbuf + XADDR(row, 2 * lane)) = pk;
        rbuf[row * RS + 2 * lane] = y0;
        rbuf[row * RS + 2 * lane + 1] = y1;
      }
    }
    __syncthreads();
  }

  // ---- prep epilogue: swizzled Abfs + hist from fp32 rbuf ----
  if (tid < EDIM) {
    int e = tid;
    int r = nextCheckin[NB + m];
    float a0 = rbuf[0 * RS + e] * rel[(size_t)r * EDIM + e];
    float a1 = rbuf[1 * RS + e] * rel_inv[(size_t)r * EDIM + e];
    int s = m & 7, c = e >> 3, j = e & 7;
    Abfs[m * 256 + ((c ^ s) << 3) + j] = f2bf(a0);
    Abfs[m * 256 + 128 + ((c ^ s) << 3) + j] = f2bf(a1);
    hist[(size_t)m * EDIM + e] = rbuf[11 * RS + e];
  }
}

// ---------------- scores: bf16 MFMA GEMM, 32KB LDS (B buffer reused) -------
// M=512 N=100000 K=256. One block per 64-col N-strip (1563 blocks). B staged
// once into the 32KB buffer, fragments hoisted to 32 VGPRs, then the SAME
// buffer serves as the A staging target (B's LDS is dead after the hoist).
// LDS 64->32KB: 5 blocks/CU resident -> barrier drains overlap across blocks.
__global__ __launch_bounds__(256, 4) void score_kernel(
    const short* __restrict__ Abfs, const float* __restrict__ ent,
    const float* __restrict__ ent_t, float* __restrict__ out) {
  __shared__ char lds[32768];  // B strip, then A chunks

  int tid = threadIdx.x;
  int wave = tid >> 6;
  int lane = tid & 63;
  int nbase = blockIdx.x * 64;

  // ---- stage B strip: 64 rows x 256 k fp32 -> bf16, swizzled ds_write ----
#pragma unroll
  for (int i = 0; i < 16; ++i) {
    int flat = i * 256 + tid;
    int row = flat >> 6;
    int c4 = flat & 63;
    int n = nbase + row;
    float4 v = make_float4(0.f, 0.f, 0.f, 0.f);
    if (n < N_ENT) {
      const float* src = (c4 < 32) ? ent + (size_t)n * 128 + c4 * 4
                                   : ent_t + (size_t)n * 128 + (c4 - 32) * 4;
      v = *(const float4*)src;
    }
    short4 bb;
    bb.x = f2bf(v.x); bb.y = f2bf(v.y); bb.z = f2bf(v.z); bb.w = f2bf(v.w);
    int chunk = c4 >> 1, half = c4 & 1;
    *(short4*)(lds + row * 512 + ((chunk ^ (row & 7)) << 4) + half * 8) = bb;
  }
  __syncthreads();  // B visible

  int q = lane >> 4;
  int lr = lane & 15;
  int rb = wave * 16 + lr;
  int col = nbase + rb;
  bool cvalid = (col < N_ENT);

  // hoist B fragments for all 8 k-steps into registers (B LDS dead after)
  bf16x8 bfr[8];
#pragma unroll
  for (int ks = 0; ks < 8; ++ks) {
    int cg = ks * 4 + q;
    bfr[ks] = *(const bf16x8*)(lds + rb * 512 + ((cg ^ (rb & 7)) << 4));
  }

  const char* gA = (const char*)Abfs;
  f32x4 acc[4];

  for (int mc = 0; mc < 8; ++mc) {
    __syncthreads();  // prev chunk's (or hoist's) LDS reads done
    // ---- stage A chunk (64 rows = 32 KB), 8 KB per wave ----
#pragma unroll
    for (int it = 0; it < 8; ++it) {
      int off = wave * 8192 + it * 1024;
      __builtin_amdgcn_global_load_lds(
          (const __attribute__((address_space(1))) uint32_t*)(
              gA + (size_t)mc * 32768 + off + lane * 16),
          (__attribute__((address_space(3))) uint32_t*)(lds + off), 16, 0, 0);
    }
    __syncthreads();  // staging complete

#pragma unroll
    for (int mi = 0; mi < 4; ++mi)
#pragma unroll
      for (int r = 0; r < 4; ++r) acc[mi][r] = 0.0f;

#pragma unroll
    for (int ks = 0; ks < 8; ++ks) {
      int cg = ks * 4 + q;
#pragma unroll
      for (int mi = 0; mi < 4; ++mi) {
        int ra = mi * 16 + lr;
        bf16x8 afrag = *(const bf16x8*)(lds + ra * 512 + ((cg ^ (ra & 7)) << 4));
        acc[mi] = __builtin_amdgcn_mfma_f32_16x16x32_bf16(afrag, bfr[ks], acc[mi], 0, 0, 0);
      }
    }

    if (cvalid) {
#pragma unroll
      for (int mi = 0; mi < 4; ++mi) {
        int mrow = mc * 64 + mi * 16 + q * 4;
#pragma unroll
        for (int r = 0; r < 4; ++r) {
          float v = acc[mi][r] * 0.5f;
          v = fminf(fmaxf(v, -20.0f), 20.0f);
          out[(size_t)(mrow + r) * N_ENT + col] = v;
        }
      }
    }
  }
}

extern "C" void kernel_launch(void* const* d_in, const int* in_sizes, int n_in,
                              void* d_out, int out_size, void* d_ws,
                              size_t ws_size, hipStream_t stream) {
  const int* inp = (const int*)d_in[0];
  const int* nextCheckin = (const int*)d_in[1];
  const float* ctxSub = (const float*)d_in[2];
  const float* ent = (const float*)d_in[3];
  const float* ent_t = (const float*)d_in[4];
  const float* rel = (const float*)d_in[5];
  const float* rel_inv = (const float*)d_in[6];
  const float* ctx = (const float*)d_in[7];
  const float* Wqkv = (const float*)d_in[8];
  const float* bqkv = (const float*)d_in[9];
  const float* Wo = (const float*)d_in[10];
  const float* bo = (const float*)d_in[11];
  const float* W1 = (const float*)d_in[12];
  const float* b1 = (const float*)d_in[13];
  const float* W2 = (const float*)d_in[14];
  const float* b2 = (const float*)d_in[15];
  const float* g1 = (const float*)d_in[16];
  const float* be1 = (const float*)d_in[17];
  const float* g2 = (const float*)d_in[18];
  const float* be2 = (const float*)d_in[19];
  float* out = (float*)d_out;

  short* Abfs = (short*)d_ws;                         // 256 KB
  short* Wbf = (short*)((char*)d_ws + 262144);        // 768 KB bf16 weights
  float* hist = out + (size_t)NB * N_ENT;

  wbf_kernel<<<1536, 256, 0, stream>>>(Wqkv, Wo, W1, W2, Wbf);
  encoder_fused<<<NB, 256, 0, stream>>>(
      inp, nextCheckin, ctxSub, ent, ent_t, rel, rel_inv, ctx, Wbf, bqkv, bo,
      b1, b2, g1, be1, g2, be2, Abfs, hist);
  score_kernel<<<1563, 256, 0, stream>>>(Abfs, ent, ent_t, out);
}